// Round 1
// baseline (6190.758 us; speedup 1.0000x reference)
//
#include <hip/hip_runtime.h>
#include <hip/hip_fp16.h>

typedef _Float16 h16;
typedef _Float16 half8 __attribute__((ext_vector_type(8)));
typedef _Float16 half4v __attribute__((ext_vector_type(4)));
typedef float f32x4 __attribute__((ext_vector_type(4)));
typedef unsigned long long u64;

#define NB 128
#define NS 2048
#define NH 512
#define NV 128
#define NE 256

// workspace layout (bytes)
#define WS_M2    0            // float [128][512]  : emb@Wx + bx + bh
#define WS_WHT   (256*1024)   // h16   [512][512]  : WhT[n][k] = Wh[k][n]
#define WS_WFCT  (768*1024)   // h16   [128][512]  : WfcT[v][k] = Wfc[k][v]
#define WS_EXCH  (896*1024)   // h16   [8][2][2][16][256] : [cluster][slot][side][m][n]
#define WS_FLAG  (1152*1024)  // int   [256] : flag[(c*2+side)*16]

__device__ __forceinline__ float tanh_fast(float v) {
  float e = __expf(2.0f * v);
  return 1.0f - __fdividef(2.0f, e + 1.0f);
}

// ---------------- prep: M2 table, transposed f16 weights, flag zeroing ----------------
__global__ void vrnn_prep(const float* __restrict__ emb, const float* __restrict__ Wx,
                          const float* __restrict__ bx, const float* __restrict__ Wh,
                          const float* __restrict__ bh, const float* __restrict__ Wfc,
                          unsigned char* __restrict__ ws) {
  float* M2 = (float*)(ws + WS_M2);
  h16* WhT = (h16*)(ws + WS_WHT);
  h16* WfcT = (h16*)(ws + WS_WFCT);
  int* flags = (int*)(ws + WS_FLAG);
  const int bid = blockIdx.x, tid = threadIdx.x;
  if (bid < 128) {
    __shared__ float le[NE];
    le[tid] = emb[bid*NE + tid];
    __syncthreads();
    for (int hh = 0; hh < 2; ++hh) {
      int n = tid + hh*256;
      float s = bx[n] + bh[n];
      for (int e = 0; e < NE; ++e) s = fmaf(le[e], Wx[e*NH + n], s);
      M2[bid*NH + n] = s;
    }
  } else if (bid < 192) {
    const int base = (bid - 128)*4096;
    for (int i = 0; i < 16; ++i) {
      int idx = base + i*256 + tid;           // idx = k*512 + n
      WhT[(idx & 511)*NH + (idx >> 9)] = (h16)Wh[idx];
    }
  } else if (bid < 208) {
    const int base = (bid - 192)*4096;
    for (int i = 0; i < 16; ++i) {
      int idx = base + i*256 + tid;           // idx = k*128 + v
      WfcT[(idx & 127)*NH + (idx >> 7)] = (h16)Wfc[idx];
    }
  } else {
    flags[tid] = 0;
  }
}

// ---------------- RNN scan: 8 clusters x 2 CUs, Wh register-resident ----------------
// block b: cluster c = b&7 (rows 16c..16c+15), side = b>>3 (h cols side*256..+256)
// pairing (c, c+8) -> same XCD under b%8 round-robin (perf only; correctness via agent-scope atomics)
__global__ void __launch_bounds__(256, 1)
vrnn_scan(const int* __restrict__ x, const float* __restrict__ bfc,
          float* __restrict__ out, unsigned char* __restrict__ ws) {
  const float* M2 = (const float*)(ws + WS_M2);
  const h16* WhT = (const h16*)(ws + WS_WHT);
  const h16* WfcT = (const h16*)(ws + WS_WFCT);
  h16* exch = (h16*)(ws + WS_EXCH);
  int* flags = (int*)(ws + WS_FLAG);

  const int bid = blockIdx.x;
  const int side = bid >> 3;
  const int c = bid & 7;
  const int rowbase = c*16;
  const int tid = threadIdx.x;
  const int w = tid >> 6;        // wave 0..3 (1 per SIMD)
  const int l = tid & 63;
  const int m = l & 15;          // batch row within cluster / MFMA 16-dim index
  const int g = l >> 4;          // k-chunk group 0..3
  const int swz = (m & 7) << 3;  // LDS XOR swizzle (element units)

  const int n0w = side*256 + w*64;   // this wave's Wh output columns [n0w, n0w+64)
  const int v0w = side*64 + w*16;    // this wave's Wfc output columns [v0w, v0w+16)
  const int ksOwn = side*8;          // k-steps whose h-values this CU produces
  const int ksPar = (1 - side)*8;

  __shared__ h16 hlds[2][16][NH];

  for (int i = tid; i < 16*NH/4; i += 256) ((u64*)&hlds[0][0][0])[i] = 0ull;  // h_{-1}=0

  // register-resident weight fragments. index j: 0..7 own k-half, 8..15 partner k-half
  // (static register indexing; runtime only in the address)
  half8 whf[4][16];
  half8 wfcf[16];
#pragma unroll
  for (int j = 0; j < 16; ++j) {
    const int ks = (j < 8) ? (ksOwn + j) : (ksPar + j - 8);
#pragma unroll
    for (int nt = 0; nt < 4; ++nt)
      whf[nt][j] = *(const half8*)&WhT[(n0w + nt*16 + m)*NH + ks*32 + g*8];
    wfcf[j] = *(const half8*)&WfcT[(v0w + m)*NH + ks*32 + g*8];
  }

  const f32x4 bfcf = *(const f32x4*)&bfc[v0w + g*4];

  int* flag_own = flags + (c*2 + side)*16;
  int* flag_par = flags + (c*2 + (1 - side))*16;

  const int* xrow = x + (rowbase + m)*NS;
  f32x4 ubuf[4];
  {
    const int tok0 = xrow[0];
#pragma unroll
    for (int nt = 0; nt < 4; ++nt)
      ubuf[nt] = *(const f32x4*)&M2[tok0*NH + n0w + nt*16 + g*4];
  }
  int tok_n = xrow[1];

  __syncthreads();

  for (int t = 0; t < NS; ++t) {
    const int p = t & 1;               // buffer holding h_{t-1}

    f32x4 acc[4];
#pragma unroll
    for (int nt = 0; nt < 4; ++nt) acc[nt] = ubuf[nt];   // acc pre-loaded with u_t
    f32x4 oacc = bfcf;                                    // out[t-1] accumulator

    // prefetch token t+2 and gather u_{t+1} (independent of h -> hides under compute)
    const int tok_use = tok_n;
    tok_n = xrow[(t + 2 < NS) ? (t + 2) : (NS - 1)];
#pragma unroll
    for (int nt = 0; nt < 4; ++nt)
      ubuf[nt] = *(const f32x4*)&M2[tok_use*NH + n0w + nt*16 + g*4];

    // ---- C1: MFMA over own k-half (data produced locally last step) ----
    {
      half8 bfr[8];
#pragma unroll
      for (int i = 0; i < 8; ++i)
        bfr[i] = *(const half8*)&hlds[p][m][(((ksOwn + i)*32) + g*8) ^ swz];
#pragma unroll
      for (int i = 0; i < 8; ++i) {
#pragma unroll
        for (int nt = 0; nt < 4; ++nt)
          acc[nt] = __builtin_amdgcn_mfma_f32_16x16x32_f16(whf[nt][i], bfr[i], acc[nt], 0, 0, 0);
        oacc = __builtin_amdgcn_mfma_f32_16x16x32_f16(wfcf[i], bfr[i], oacc, 0, 0, 0);
      }
    }

    // ---- import partner's h_{t-1} half (latency hidden under C1) ----
    if (t > 0) {
      while (__hip_atomic_load(flag_par, __ATOMIC_ACQUIRE, __HIP_MEMORY_SCOPE_AGENT) < t)
        __builtin_amdgcn_s_sleep(1);
      const h16* src = exch + ((c*2 + ((t - 1) & 1))*2 + (1 - side))*4096;
      const int mm = w*4 + g;
      const int nch = (l & 15)*16;
      u64* sp = (u64*)&src[mm*256 + nch];
      const u64 d0 = __hip_atomic_load(sp + 0, __ATOMIC_RELAXED, __HIP_MEMORY_SCOPE_AGENT);
      const u64 d1 = __hip_atomic_load(sp + 1, __ATOMIC_RELAXED, __HIP_MEMORY_SCOPE_AGENT);
      const u64 d2 = __hip_atomic_load(sp + 2, __ATOMIC_RELAXED, __HIP_MEMORY_SCOPE_AGENT);
      const u64 d3 = __hip_atomic_load(sp + 3, __ATOMIC_RELAXED, __HIP_MEMORY_SCOPE_AGENT);
      const int swzm = (mm & 7) << 3;
      const int pk = (1 - side)*256 + nch;
      u64* q0 = (u64*)&hlds[p][mm][(pk) ^ swzm];
      u64* q1 = (u64*)&hlds[p][mm][(pk + 8) ^ swzm];
      q0[0] = d0; q0[1] = d1;
      q1[0] = d2; q1[1] = d3;
    }
    __syncthreads();

    // ---- C2: MFMA over partner k-half ----
    {
      half8 bfr[8];
#pragma unroll
      for (int i = 0; i < 8; ++i)
        bfr[i] = *(const half8*)&hlds[p][m][(((ksPar + i)*32) + g*8) ^ swz];
#pragma unroll
      for (int i = 0; i < 8; ++i) {
#pragma unroll
        for (int nt = 0; nt < 4; ++nt)
          acc[nt] = __builtin_amdgcn_mfma_f32_16x16x32_f16(whf[nt][8 + i], bfr[i], acc[nt], 0, 0, 0);
        oacc = __builtin_amdgcn_mfma_f32_16x16x32_f16(wfcf[8 + i], bfr[i], oacc, 0, 0, 0);
      }
    }

    // fused output GEMM result for step t-1
    if (t > 0) {
      float* po = out + ((size_t)(rowbase + m)*NS + (t - 1))*NV + v0w + g*4;
      *(f32x4*)po = oacc;
    }

    // ---- tanh, publish h_t to LDS (next buffer) and to partner via LLC ----
    {
      const int pn = p ^ 1;
      h16* exo = exch + ((c*2 + p)*2 + side)*4096;
#pragma unroll
      for (int nt = 0; nt < 4; ++nt) {
        const f32x4 a = acc[nt];
        half4v hv;
#pragma unroll
        for (int r = 0; r < 4; ++r) hv[r] = (h16)tanh_fast(a[r]);
        const int kb = n0w + nt*16 + g*4;
        *(half4v*)&hlds[pn][m][kb ^ swz] = hv;
        union { half4v v; u64 u; } cv; cv.v = hv;
        __hip_atomic_store((u64*)&exo[m*256 + (w*64 + nt*16 + g*4)], cv.u,
                           __ATOMIC_RELAXED, __HIP_MEMORY_SCOPE_AGENT);
      }
    }
    __syncthreads();  // drains vmcnt for all waves' exch stores before flag release
    if (tid == 0)
      __hip_atomic_store(flag_own, t + 1, __ATOMIC_RELEASE, __HIP_MEMORY_SCOPE_AGENT);
  }

  // ---- tail: out[S-1] = h_{S-1}@Wfc + bfc (h_{S-1} lives in hlds[0]) ----
  {
    f32x4 oacc = bfcf;
    {
      half8 bfr[8];
#pragma unroll
      for (int i = 0; i < 8; ++i)
        bfr[i] = *(const half8*)&hlds[0][m][(((ksOwn + i)*32) + g*8) ^ swz];
#pragma unroll
      for (int i = 0; i < 8; ++i)
        oacc = __builtin_amdgcn_mfma_f32_16x16x32_f16(wfcf[i], bfr[i], oacc, 0, 0, 0);
    }
    while (__hip_atomic_load(flag_par, __ATOMIC_ACQUIRE, __HIP_MEMORY_SCOPE_AGENT) < NS)
      __builtin_amdgcn_s_sleep(1);
    {
      const h16* src = exch + ((c*2 + 1)*2 + (1 - side))*4096;  // slot (S-1)&1 = 1
      const int mm = w*4 + g;
      const int nch = (l & 15)*16;
      u64* sp = (u64*)&src[mm*256 + nch];
      const u64 d0 = __hip_atomic_load(sp + 0, __ATOMIC_RELAXED, __HIP_MEMORY_SCOPE_AGENT);
      const u64 d1 = __hip_atomic_load(sp + 1, __ATOMIC_RELAXED, __HIP_MEMORY_SCOPE_AGENT);
      const u64 d2 = __hip_atomic_load(sp + 2, __ATOMIC_RELAXED, __HIP_MEMORY_SCOPE_AGENT);
      const u64 d3 = __hip_atomic_load(sp + 3, __ATOMIC_RELAXED, __HIP_MEMORY_SCOPE_AGENT);
      const int swzm = (mm & 7) << 3;
      const int pk = (1 - side)*256 + nch;
      u64* q0 = (u64*)&hlds[0][mm][(pk) ^ swzm];
      u64* q1 = (u64*)&hlds[0][mm][(pk + 8) ^ swzm];
      q0[0] = d0; q0[1] = d1;
      q1[0] = d2; q1[1] = d3;
    }
    __syncthreads();
    {
      half8 bfr[8];
#pragma unroll
      for (int i = 0; i < 8; ++i)
        bfr[i] = *(const half8*)&hlds[0][m][(((ksPar + i)*32) + g*8) ^ swz];
#pragma unroll
      for (int i = 0; i < 8; ++i)
        oacc = __builtin_amdgcn_mfma_f32_16x16x32_f16(wfcf[8 + i], bfr[i], oacc, 0, 0, 0);
    }
    float* po = out + ((size_t)(rowbase + m)*NS + (NS - 1))*NV + v0w + g*4;
    *(f32x4*)po = oacc;
  }
}

extern "C" void kernel_launch(void* const* d_in, const int* in_sizes, int n_in,
                              void* d_out, int out_size, void* d_ws, size_t ws_size,
                              hipStream_t stream) {
  (void)in_sizes; (void)n_in; (void)out_size; (void)ws_size;
  const int*   x   = (const int*)d_in[0];
  const float* emb = (const float*)d_in[1];
  const float* Wx  = (const float*)d_in[2];
  const float* bx  = (const float*)d_in[3];
  const float* Wh  = (const float*)d_in[4];
  const float* bh  = (const float*)d_in[5];
  const float* Wfc = (const float*)d_in[6];
  const float* bfc = (const float*)d_in[7];
  float* out = (float*)d_out;
  unsigned char* ws = (unsigned char*)d_ws;

  hipLaunchKernelGGL(vrnn_prep, dim3(209), dim3(256), 0, stream,
                     emb, Wx, bx, Wh, bh, Wfc, ws);
  hipLaunchKernelGGL(vrnn_scan, dim3(16), dim3(256), 0, stream,
                     x, bfc, out, ws);
}